// Round 12
// baseline (152.393 us; speedup 1.0000x reference)
//
#include <hip/hip_runtime.h>
#include <stdint.h>

// Problem constants
constexpr int NBATCH = 4;
constexpr int CH     = 256;   // channels
constexpr int LEN    = 4096;  // sequence length
constexpr int LPOOL  = 1024;  // pooled length (LEN/4)
constexpr int NH     = 4;     // heads
constexpr int HD     = 64;    // head dim

typedef __attribute__((ext_vector_type(8))) short short8;     // 8 bf16 in 4 VGPRs
typedef __attribute__((ext_vector_type(4))) float float4e;    // MFMA C/D 16x16
typedef __attribute__((ext_vector_type(16))) float float16e;  // MFMA C/D 32x32
typedef __attribute__((ext_vector_type(2))) unsigned uint2v;

__device__ __forceinline__ unsigned short f2bf(float f) {
    union { unsigned int i; float f; } v; v.f = f;
    unsigned int lsb = (v.i >> 16) & 1u;
    v.i += 0x7fffu + lsb;
    return (unsigned short)(v.i >> 16);
}
// pack two floats -> two bf16 (round-half-up via +0x8000, then byte-perm)
__device__ __forceinline__ unsigned pack2bf(float lo, float hi) {
    unsigned a = __float_as_uint(lo) + 0x8000u;
    unsigned b = __float_as_uint(hi) + 0x8000u;
    return __builtin_amdgcn_perm(b, a, 0x07060302u);
}
// single-instruction 2^x (OCML exp2f without fast-math is ~12 VALU ops)
__device__ __forceinline__ float fast_exp2(float x) {
#if __has_builtin(__builtin_amdgcn_exp2f)
    return __builtin_amdgcn_exp2f(x);
#else
    float r;
    asm("v_exp_f32 %0, %1" : "=v"(r) : "v"(x));
    return r;
#endif
}
// async global->LDS DMA, 16B per lane; LDS dest = wave-uniform base + lane*16
__device__ __forceinline__ void gload16(const void* g, void* l) {
    __builtin_amdgcn_global_load_lds(
        (const __attribute__((address_space(1))) unsigned int*)g,
        (__attribute__((address_space(3))) unsigned int*)l, 16, 0, 0);
}

// ---------------------------------------------------------------------------
// Phase A body (correctness-proven r9/r10): b in [0,1024) transpose+pool;
// [1024,1344) weight cast; 1344 BN affine + bkv.
__device__ __forceinline__ void transpool_block(
    int b, char* smemc,
    const float* __restrict__ x, unsigned short* __restrict__ xbf,
    unsigned short* __restrict__ poolT,
    const float* __restrict__ w0, const float* __restrict__ w1,
    const float* __restrict__ w2, const float* __restrict__ w3,
    const float* __restrict__ w4, unsigned short* __restrict__ outW,
    const float* __restrict__ g1, const float* __restrict__ b1,
    const float* __restrict__ m1, const float* __restrict__ v1,
    const float* __restrict__ g2, const float* __restrict__ b2,
    const float* __restrict__ m2, const float* __restrict__ v2,
    float* __restrict__ scale, float* __restrict__ shift,
    const float* __restrict__ bk, const float* __restrict__ bv,
    float* __restrict__ bkv)
{
    float* T   = (float*)smemc;            // [64][65] = 16640 B
    float* P16 = (float*)(smemc + 16640);  // [64][17] = 4352 B
    int t = threadIdx.x;
    if (b >= 1024) {
        int sb = b - 1024;
        if (sb < 320) {
            int gid = sb * 256 + t;
            int w = gid >> 14;
            int off = (gid & 16383) * 4;
            const float* src = (w == 0) ? w0 : (w == 1) ? w1 : (w == 2) ? w2 : (w == 3) ? w3 : w4;
            float4 v = *(const float4*)(src + off);
            uint2 pk;
            pk.x = pack2bf(v.x, v.y);
            pk.y = pack2bf(v.z, v.w);
            *(uint2*)(outW + w * 65536 + off) = pk;
        } else {
            float inv1 = g1[t] * rsqrtf(v1[t] + 1e-5f);
            float inv2 = g2[t] * rsqrtf(v2[t] + 1e-5f);
            scale[t] = inv1 * inv2;
            shift[t] = (b1[t] - m1[t] * inv1) * inv2 + (b2[t] - m2[t] * inv2);
            bkv[t] = bk[t];
            bkv[256 + t] = bv[t];
        }
        return;
    }
    int n = b >> 8, c0 = ((b >> 6) & 3) * 64, l0 = (b & 63) * 64;
    const float* xp = x + ((size_t)n * CH + c0) * LEN + l0;
    #pragma unroll
    for (int i = 0; i < 4; i++) {
        int idx = t + i * 256;
        int c = idx >> 4, l4 = idx & 15;
        float4 v = *(const float4*)(xp + (size_t)c * LEN + l4 * 4);
        T[c * 65 + l4 * 4 + 0] = v.x; T[c * 65 + l4 * 4 + 1] = v.y;
        T[c * 65 + l4 * 4 + 2] = v.z; T[c * 65 + l4 * 4 + 3] = v.w;
        P16[c * 17 + l4] = (v.x + v.y + v.z + v.w) * 0.25f
                         + fmaxf(fmaxf(v.x, v.y), fmaxf(v.z, v.w));
    }
    __syncthreads();
    unsigned short* op = xbf + ((size_t)n * LEN + l0) * CH + c0;
    #pragma unroll
    for (int i = 0; i < 4; i++) {
        int idx = t + i * 256;
        int l = idx >> 4, c4 = idx & 15;
        uint2 pk;
        pk.x = pack2bf(T[(c4 * 4 + 0) * 65 + l], T[(c4 * 4 + 1) * 65 + l]);
        pk.y = pack2bf(T[(c4 * 4 + 2) * 65 + l], T[(c4 * 4 + 3) * 65 + l]);
        *(uint2*)(op + (size_t)l * CH + c4 * 4) = pk;
    }
    int p0 = l0 >> 2;
    #pragma unroll
    for (int k = 0; k < 2; k++) {
        int p = (t >> 5) + k * 8;
        int c2 = (t & 31) * 2;
        unsigned pk = pack2bf(P16[c2 * 17 + p], P16[(c2 + 1) * 17 + p]);
        *(unsigned*)(poolT + ((size_t)n * LPOOL + p0 + p) * CH + c0 + c2) = pk;
    }
}

__global__ __launch_bounds__(256) void transpool_setup(
    const float* __restrict__ x, unsigned short* __restrict__ xbf,
    unsigned short* __restrict__ poolT,
    const float* __restrict__ w0, const float* __restrict__ w1,
    const float* __restrict__ w2, const float* __restrict__ w3,
    const float* __restrict__ w4, unsigned short* __restrict__ outW,
    const float* __restrict__ g1, const float* __restrict__ b1,
    const float* __restrict__ m1, const float* __restrict__ v1,
    const float* __restrict__ g2, const float* __restrict__ b2,
    const float* __restrict__ m2, const float* __restrict__ v2,
    float* __restrict__ scale, float* __restrict__ shift,
    const float* __restrict__ bk, const float* __restrict__ bv,
    float* __restrict__ bkv)
{
    __shared__ __align__(16) char smem[20992];
    transpool_block(blockIdx.x, smem, x, xbf, poolT, w0, w1, w2, w3, w4, outW,
                    g1, b1, m1, v1, g2, b2, m2, v2, scale, shift, bk, bv, bkv);
}

// ---------------------------------------------------------------------------
// GEMM block body, TRIPLE-buffered counted-vmcnt (T4; r11 had an OOB buffer
// index "s+2" for s=1 -> buf 3 on a 3-buf array, UB -> wrong step-3 data.
// FIXED: (s+2)%3, compile-time under full unroll: s=0 -> buf2, s=1 -> buf0.
// Buf-0 reuse is race-free: every wave finished compute(buf0) in iter 0
// before its iter-1 barrier, and the step-3 DMA is issued after that barrier.)
// BM=64 x BN=64, BK=64, K=256. Per thread per K-step: 4 loads (2A+2B, one
// issue group). 2 steps in flight; at top of iter s outstanding <= 8 loads;
// vmcnt(4) -> in-order completion retires step s while s+1 stays in flight.
// Tail step uses vmcnt(0); step 3 lives in buf 0 (3%3). LDS 48 KB:
// A bufs @ 0/8K/16K, B bufs @ 24K/32K/40K. Epilogue restage uses the
// contiguous 16 KB at 24K (B bufs 0+1).
__device__ __forceinline__ void gemm_block(
    int bx, int by, int bz, char* smemc,
    const unsigned short* __restrict__ A,
    const unsigned short* __restrict__ B, size_t bBatch,
    const float* __restrict__ biasRow,
    const float* __restrict__ scale, const float* __restrict__ shift,
    float* __restrict__ outF, size_t oFBatch,
    unsigned short* __restrict__ out1, size_t o1Batch, int cs1,
    unsigned short* __restrict__ out2, size_t o2Batch, int rs2, int rowSplit,
    int NN, float outScale)
{
    char* AsB[3] = { smemc,         smemc + 8192,  smemc + 16384 };
    char* BsB[3] = { smemc + 24576, smemc + 32768, smemc + 40960 };

    int n = bz;
    int t = threadIdx.x;
    int wave = t >> 6, lane = t & 63, m = lane & 15, quad = lane >> 4;
    int wm = wave & 1, wn = wave >> 1;
    int rowTile = by * 64;
    int col0 = bx * 64;

    const unsigned short* Ab = A + (size_t)rowTile * 256;
    const unsigned short* Bb = B + (size_t)n * bBatch + (size_t)col0 * 256;

    float4e acc[2][2] = {};

    int srow[2], sch[2], ldsW[2];
    #pragma unroll
    for (int i = 0; i < 2; i++) {
        int idx = t + i * 256;
        srow[i] = idx >> 3;
        sch[i]  = idx & 7;
        ldsW[i] = wave * 1024 + i * 4096;
    }
    int aoff[2][2], boff[2][2];
    #pragma unroll
    for (int i = 0; i < 2; i++) {
        int ra = wm * 32 + i * 16 + m;
        int rb = wn * 32 + i * 16 + m;
        #pragma unroll
        for (int kc = 0; kc < 2; kc++) {
            aoff[i][kc] = ra * 128 + kc * 64 + quad * 16;
            boff[i][kc] = rb * 128 + kc * 64 + quad * 16;
        }
    }

    // one issue-group = 4 loads per thread per K-step (2 A + 2 B)
    auto issue_step = [&](int s, int buf) {
        int kk = s * 64;
        #pragma unroll
        for (int i = 0; i < 2; i++)
            gload16(Ab + (size_t)srow[i] * 256 + kk + sch[i] * 8, AsB[buf] + ldsW[i]);
        #pragma unroll
        for (int i = 0; i < 2; i++)
            gload16(Bb + (size_t)srow[i] * 256 + kk + sch[i] * 8, BsB[buf] + ldsW[i]);
    };

    auto step_compute = [&](const char* AsC, const char* BsC) {
        #pragma unroll
        for (int kc = 0; kc < 2; kc++) {
            short8 af[2], bfr[2];
            #pragma unroll
            for (int i = 0; i < 2; i++) {
                af[i]  = *(const short8*)(AsC + aoff[i][kc]);
                bfr[i] = *(const short8*)(BsC + boff[i][kc]);
            }
            __builtin_amdgcn_s_setprio(1);
            #pragma unroll
            for (int i = 0; i < 2; i++)
                #pragma unroll
                for (int j = 0; j < 2; j++)
                    acc[i][j] = __builtin_amdgcn_mfma_f32_16x16x32_bf16(af[i], bfr[j], acc[i][j], 0, 0, 0);
            __builtin_amdgcn_s_setprio(0);
        }
    };

    // prologue: K-steps 0,1 -> bufs 0,1 (two issue-groups, in order)
    issue_step(0, 0);
    issue_step(1, 1);

    #pragma unroll
    for (int s = 0; s < 3; s++) {
        // step s's 4 loads complete (step s+1's 4 may remain in flight)
        asm volatile("s_waitcnt vmcnt(4)" ::: "memory");
        __builtin_amdgcn_sched_barrier(0);
        __builtin_amdgcn_s_barrier();
        __builtin_amdgcn_sched_barrier(0);
        if (s < 2)
            issue_step(s + 2, (s + 2) % 3);   // s=0: step2->buf2; s=1: step3->buf0
        step_compute(AsB[s], BsB[s]);
    }
    // tail: step 3 (in buf 0); only its 4 loads can be outstanding
    asm volatile("s_waitcnt vmcnt(0)" ::: "memory");
    __builtin_amdgcn_sched_barrier(0);
    __builtin_amdgcn_s_barrier();
    __builtin_amdgcn_sched_barrier(0);
    step_compute(AsB[0], BsB[0]);
    __syncthreads();

    if (outF) {
        float* TOf = (float*)(smemc + 24576);   // 64x64 f32 = 16 KB (B bufs 0+1)
        float* dst = outF + (size_t)n * oFBatch;
        #pragma unroll
        for (int i = 0; i < 2; i++) {
            int rowL = wm * 32 + i * 16 + quad * 4;
            int rowG = rowTile + rowL;
            float br[4], sc[4], sh[4];
            #pragma unroll
            for (int r = 0; r < 4; r++) {
                br[r] = biasRow ? biasRow[rowG + r] : 0.0f;
                sc[r] = scale ? scale[rowG + r] : 1.0f;
                sh[r] = shift ? shift[rowG + r] : 0.0f;
            }
            #pragma unroll
            for (int j = 0; j < 2; j++) {
                int colL = wn * 32 + j * 16 + m;
                float4e c = acc[i][j];
                #pragma unroll
                for (int r = 0; r < 4; r++)
                    TOf[(rowL + r) * 64 + colL] = ((c[r] + br[r]) * sc[r] + sh[r]) * outScale;
            }
        }
        __syncthreads();
        #pragma unroll
        for (int w = 0; w < 4; w++) {
            int idx = t + w * 256;
            int row = idx >> 4, c4 = idx & 15;
            *(float4*)(dst + (size_t)(rowTile + row) * NN + col0 + c4 * 4) =
                *(const float4*)&TOf[row * 64 + c4 * 4];
        }
        return;
    }

    bool mode2 = (rowTile >= rowSplit);
    unsigned short* TO = (unsigned short*)(smemc + 24576);
    #pragma unroll
    for (int i = 0; i < 2; i++) {
        int rowL = wm * 32 + i * 16 + quad * 4;
        int rowG = rowTile + rowL;
        float br[4], sc[4], sh[4];
        #pragma unroll
        for (int r = 0; r < 4; r++) {
            br[r] = biasRow ? biasRow[rowG + r] : 0.0f;
            sc[r] = scale ? scale[rowG + r] : 1.0f;
            sh[r] = shift ? shift[rowG + r] : 0.0f;
        }
        #pragma unroll
        for (int j = 0; j < 2; j++) {
            int colL = wn * 32 + j * 16 + m;
            float4e c = acc[i][j];
            float v0 = ((c[0] + br[0]) * sc[0] + sh[0]) * outScale;
            float v1 = ((c[1] + br[1]) * sc[1] + sh[1]) * outScale;
            float v2 = ((c[2] + br[2]) * sc[2] + sh[2]) * outScale;
            float v3 = ((c[3] + br[3]) * sc[3] + sh[3]) * outScale;
            if (!mode2) {
                uint2 pk;
                pk.x = pack2bf(v0, v1);
                pk.y = pack2bf(v2, v3);
                *(uint2*)&TO[colL * 72 + rowL] = pk;
            } else {
                TO[(rowL + 0) * 72 + colL] = f2bf(v0);
                TO[(rowL + 1) * 72 + colL] = f2bf(v1);
                TO[(rowL + 2) * 72 + colL] = f2bf(v2);
                TO[(rowL + 3) * 72 + colL] = f2bf(v3);
            }
        }
    }
    __syncthreads();
    if (!mode2) {
        unsigned short* dst = out1 + (size_t)n * o1Batch;
        #pragma unroll
        for (int w = 0; w < 2; w++) {
            int idx = t + w * 256;
            int l = idx >> 3, ch = idx & 7;
            *(uint4*)(dst + (size_t)(col0 + l) * cs1 + rowTile + ch * 8) =
                *(const uint4*)&TO[l * 72 + ch * 8];
        }
    } else {
        unsigned short* dst = out2 + (size_t)n * o2Batch;
        int rowBase = rowTile - rowSplit;
        #pragma unroll
        for (int w = 0; w < 2; w++) {
            int idx = t + w * 256;
            int row = idx >> 3, ch = idx & 7;
            *(uint4*)(dst + (size_t)(rowBase + row) * rs2 + col0 + ch * 8) =
                *(const uint4*)&TO[row * 72 + ch * 8];
        }
    }
}

// generic single-job GEMM wrapper (kv, o-proj)
__global__ __launch_bounds__(256, 4) void gemm_single(
    const unsigned short* __restrict__ A,
    const unsigned short* __restrict__ B, size_t bBatch,
    const float* __restrict__ biasRow,
    const float* __restrict__ scale, const float* __restrict__ shift,
    float* __restrict__ outF, size_t oFBatch,
    unsigned short* __restrict__ out1, size_t o1Batch, int cs1,
    unsigned short* __restrict__ out2, size_t o2Batch, int rs2, int rowSplit,
    int NN, float outScale)
{
    __shared__ __align__(16) char smem[49152];
    gemm_block(blockIdx.x, blockIdx.y, blockIdx.z, smem, A, B, bBatch,
               biasRow, scale, shift, outF, oFBatch,
               out1, o1Batch, cs1, out2, o2Batch, rs2, rowSplit, NN, outScale);
}

// merged q-proj + xa kernel (independent GEMMs, one dispatch)
__global__ __launch_bounds__(256, 4) void gemm_qxa(
    const unsigned short* __restrict__ Wqbf, const unsigned short* __restrict__ xbf,
    const float* __restrict__ bq, unsigned short* __restrict__ Qbf,
    const unsigned short* __restrict__ Wabf, const unsigned short* __restrict__ poolT,
    const float* __restrict__ bn_scale, const float* __restrict__ bn_shift,
    unsigned short* __restrict__ xabf)
{
    __shared__ __align__(16) char smem[49152];
    int bx = blockIdx.x;
    if (bx < 64) {
        gemm_block(bx, blockIdx.y, blockIdx.z, smem, Wqbf, xbf, (size_t)LEN * CH,
                   bq, nullptr, nullptr, nullptr, 0,
                   Qbf, (size_t)LEN * CH, 256, nullptr, 0, 0, 1 << 30,
                   LEN, 0.18033688f);
    } else {
        gemm_block(bx - 64, blockIdx.y, blockIdx.z, smem, Wabf, poolT, (size_t)LPOOL * CH,
                   nullptr, bn_scale, bn_shift, nullptr, 0,
                   xabf, (size_t)LPOOL * CH, 256, nullptr, 0, 0, 1 << 30,
                   LPOOL, 1.0f);
    }
}

// ---------------------------------------------------------------------------
// MFMA flash attention, 32x32x16, TRIPLE-buffered counted-vmcnt. Byte-identical
// to the passing r10 version. Do not touch.
__global__ __launch_bounds__(256, 2) void attn_mfma(
    const unsigned short* __restrict__ Qb,
    const unsigned short* __restrict__ Kb,
    const unsigned short* __restrict__ Vb,
    unsigned short* __restrict__ Obf)
{
    __shared__ unsigned short Ks[3][64 * 64];   // [key][dim], swizzled content
    __shared__ unsigned short Vs[3][64 * 64];   // [e][key],  swizzled content

    int qb = blockIdx.x;          // 128-row q block
    int h  = blockIdx.y;
    int n  = blockIdx.z;
    int t  = threadIdx.x;
    int wave = t >> 6, lane = t & 63;
    int col = lane & 31;          // q within wave
    int hi  = lane >> 5;
    int l0 = qb * 128 + wave * 32;

    const unsigned short* qp = Qb + ((size_t)n * LEN + l0 + col) * CH + h * HD + hi * 8;
    short8 bQ[4];
    #pragma unroll
    for (int dc = 0; dc < 4; dc++)
        bQ[dc] = *(const short8*)(qp + dc * 16);

    float16e Oa[2];
    #pragma unroll
    for (int e = 0; e < 2; e++)
        #pragma unroll
        for (int r = 0; r < 16; r++) Oa[e][r] = 0.0f;
    float l_run = 0.0f;

    const unsigned short* KgBase = Kb + (size_t)n * LPOOL * CH + h * HD;
    const unsigned short* VgBase = Vb + ((size_t)n * CH + h * HD) * LPOOL;
    const float NEG = -17.312340f;   // -12 * log2(e)

    int srow[2], schs[2], ldsb[2];
    #pragma unroll
    for (int i = 0; i < 2; i++) {
        int idx = t + i * 256;
        srow[i] = idx >> 3;
        schs[i] = (idx & 7) ^ (srow[i] & 7);
        ldsb[i] = wave * 1024 + i * 4096;   // wave-uniform DMA base (bytes)
    }
    int ldoff[2][4];
    #pragma unroll
    for (int g = 0; g < 2; g++)
        #pragma unroll
        for (int c = 0; c < 4; c++) {
            int row = g * 32 + col;
            ldoff[g][c] = row * 128 + ((c * 32 + hi * 16) ^ ((row & 7) << 4));
        }

    auto issue_tile = [&](int tile, int buf) {
        const unsigned short* ksrc = KgBase + (size_t)tile * 64 * CH;
        const unsigned short* vsrc = VgBase + tile * 64;
        #pragma unroll
        for (int i = 0; i < 2; i++)
            gload16(ksrc + (size_t)srow[i] * CH + schs[i] * 8, (char*)Ks[buf] + ldsb[i]);
        #pragma unroll
        for (int i = 0; i < 2; i++)
            gload16(vsrc + (size_t)srow[i] * LPOOL + schs[i] * 8, (char*)Vs[buf] + ldsb[i]);
    };

    auto tile_compute = [&](const char* KsC, const char* VsC) {
        #pragma unroll
        for (int kh = 0; kh < 2; kh++) {
            float16e c;
            #pragma unroll
            for (int r = 0; r < 16; r++) c[r] = NEG;
            __builtin_amdgcn_s_setprio(1);
            #pragma unroll
            for (int dc = 0; dc < 4; dc++) {
                short8 a = *(const short8*)(KsC + ldoff[kh][dc]);
                c = __builtin_amdgcn_mfma_f32_32x32x16_bf16(a, bQ[dc], c, 0, 0, 0);
            }
            __builtin_amdgcn_s_setprio(0);
            float p[16];
            #pragma unroll
            for (int r = 0; r < 16; r++) p[r] = fast_exp2(c[r]);
            l_run += ((p[0] + p[1]) + (p[2] + p[3])) + ((p[4] + p[5]) + (p[6] + p[7]))
                   + ((p[8] + p[9]) + (p[10] + p[11])) + ((p[12] + p[13]) + (p[14] + p[15]));
            union { unsigned u[4]; short8 s; } bP[2];
            #pragma unroll
            for (int kc2 = 0; kc2 < 2; kc2++) {
                int rb = kc2 * 8;
                unsigned A0 = pack2bf(p[rb + 0], p[rb + 1]);
                unsigned B0 = pack2bf(p[rb + 4], p[rb + 5]);
                unsigned A1 = pack2bf(p[rb + 2], p[rb + 3]);
                unsigned B1 = pack2bf(p[rb + 6], p[rb + 7]);
                uint2v s0 = __builtin_amdgcn_permlane32_swap(A0, B0, false, false);
                uint2v s1 = __builtin_amdgcn_permlane32_swap(A1, B1, false, false);
                bP[kc2].u[0] = s0[0];
                bP[kc2].u[1] = s1[0];
                bP[kc2].u[2] = s0[1];
                bP[kc2].u[3] = s1[1];
            }
            __builtin_amdgcn_s_setprio(1);
            #pragma unroll
            for (int eh = 0; eh < 2; eh++)
                #pragma unroll
                for (int kc2 = 0; kc2 < 2; kc2++) {
                    short8 av = *(const short8*)(VsC + ldoff[eh][kh * 2 + kc2]);
                    Oa[eh] = __builtin_amdgcn_mfma_f32_32x32x16_bf16(av, bP[kc2].s, Oa[eh], 0, 0, 0);
                }
            __builtin_amdgcn_s_setprio(0);
        }
    };

    issue_tile(0, 0);
    issue_tile(1, 1);

    int cur = 0;
    #pragma unroll 3
    for (int kt = 0; kt < 15; kt++) {
        asm volatile("s_waitcnt vmcnt(4)" ::: "memory");
        __builtin_amdgcn_sched_barrier(0);
        __builtin_amdgcn_s_barrier();
        __builtin_amdgcn_sched_barrier(0);
        if (kt < 14) {
            int nb = cur - 1; if (nb < 0) nb = 2;   // (cur+2)%3
            issue_tile(kt + 2, nb);
        }
        tile_compute((const char*)Ks[cur], (const char*)Vs[cur]);
        cur = (cur == 2) ? 0 : cur + 1;
    }
    asm volatile("s_waitcnt vmcnt(0)" ::: "memory");
    __builtin_amdgcn_sched_barrier(0);
    __builtin_amdgcn_s_barrier();
    __builtin_amdgcn_sched_barrier(0);
    tile_compute((const char*)Ks[cur], (const char*)Vs[cur]);

    float l = l_run + __shfl_xor(l_run, 32);
    float inv = 1.0f / l;
    unsigned short* op = Obf + ((size_t)n * LEN + l0 + col) * CH + h * HD + hi * 4;
    #pragma unroll
    for (int eh = 0; eh < 2; eh++)
        #pragma unroll
        for (int rq = 0; rq < 4; rq++) {
            int r = rq * 4;
            uint2 pk;
            pk.x = pack2bf(Oa[eh][r + 0] * inv, Oa[eh][r + 1] * inv);
            pk.y = pack2bf(Oa[eh][r + 2] * inv, Oa[eh][r + 3] * inv);
            *(uint2*)(op + eh * 32 + rq * 8) = pk;
        }
}

// ---------------------------------------------------------------------------
extern "C" void kernel_launch(void* const* d_in, const int* in_sizes, int n_in,
                              void* d_out, int out_size, void* d_ws, size_t ws_size,
                              hipStream_t stream)
{
    const float* x  = (const float*)d_in[0];
    const float* Wq = (const float*)d_in[1];
    const float* bq = (const float*)d_in[2];
    const float* Wk = (const float*)d_in[3];
    const float* bk = (const float*)d_in[4];
    const float* Wv = (const float*)d_in[5];
    const float* bv = (const float*)d_in[6];
    const float* Wo = (const float*)d_in[7];
    const float* bo = (const float*)d_in[8];
    const float* Wa = (const float*)d_in[9];
    const float* g1 = (const float*)d_in[10];
    const float* b1 = (const float*)d_in[11];
    const float* m1 = (const float*)d_in[12];
    const float* v1 = (const float*)d_in[13];
    const float* g2 = (const float*)d_in[14];
    const float* b2 = (const float*)d_in[15];
    const float* m2 = (const float*)d_in[16];
    const float* v2 = (const float*)d_in[17];

    float* wsf      = (float*)d_ws;
    float* bn_scale = wsf;            // 256
    float* bn_shift = wsf + 256;      // 256
    float* bkv      = wsf + 512;      // 512
    unsigned short* Wbf   = (unsigned short*)(wsf + 1024);          // 5*65536
    unsigned short* xbf   = Wbf + 5 * 65536;                        // [N,L,C]
    unsigned short* poolT = xbf   + (size_t)NBATCH * LEN * CH;      // [N,L2,C]
    unsigned short* xabf  = poolT + (size_t)NBATCH * LPOOL * CH;    // [N,L2,C]
    unsigned short* Kbf   = xabf  + (size_t)NBATCH * LPOOL * CH;    // [N,L2,C]
    unsigned short* Vbf   = Kbf   + (size_t)NBATCH * LPOOL * CH;    // [N,C,L2]
    unsigned short* Qbf   = Vbf   + (size_t)NBATCH * LPOOL * CH;    // [N,L,C]
    unsigned short* Obf   = Qbf   + (size_t)NBATCH * LEN * CH;      // [N,L,C]

    // 1. transpose+pool over x, weights->bf16, BN affine, bkv concat
    transpool_setup<<<1345, 256, 0, stream>>>(x, xbf, poolT,
        Wq, Wk, Wv, Wo, Wa, Wbf,
        g1, b1, m1, v1, g2, b2, m2, v2, bn_scale, bn_shift, bk, bv, bkv);

    // 2. merged: q = Wq @ x + bq (bx<64) AND xa = BN(Wa @ pool) (bx>=64)
    gemm_qxa<<<dim3(80, 4, 4), 256, 0, stream>>>(
        Wbf + 0 * 65536, xbf, bq, Qbf,
        Wbf + 4 * 65536, poolT, bn_scale, bn_shift, xabf);

    // 3. fused k+v: A = [Wk;Wv], M=512. rows 0..255 -> Kbf [l2][c];
    //    rows 256..511 -> Vbf [c][l2]
    gemm_single<<<dim3(16, 8, 4), 256, 0, stream>>>(
        Wbf + 1 * 65536, xabf, (size_t)LPOOL * CH, bkv, nullptr, nullptr,
        nullptr, 0, Kbf, (size_t)LPOOL * CH, 256, Vbf, (size_t)LPOOL * CH, LPOOL, 256,
        LPOOL, 1.0f);

    // 4. attention -> Obf [N,L,C] bf16 (triple-buffered counted-vmcnt)
    attn_mfma<<<dim3(LEN / 128, NH, NBATCH), 256, 0, stream>>>(Qbf, Kbf, Vbf, Obf);

    // 5. out = Wo @ o + bo -> f32 d_out [N,C,L]
    gemm_single<<<dim3(64, 4, 4), 256, 0, stream>>>(
        Wbf + 3 * 65536, Obf, (size_t)LEN * CH, bo, nullptr, nullptr,
        (float*)d_out, (size_t)CH * LEN, nullptr, 0, 0, nullptr, 0, 0, 1 << 30,
        LEN, 1.0f);
}